// Round 4
// baseline (6350.101 us; speedup 1.0000x reference)
//
#include <hip/hip_runtime.h>

#define NHID   128
#define NSTEPS 512
#define NSAMP  4096
#define SPB    16
#define BS     1024
#define NBLK   (NSAMP / SPB)          // 256 blocks, 1 per CU
#define HPAD   132                    // h row pad: 2-way LDS aliasing max (free)
#define SAMP_ELEMS (NSAMP * NSTEPS)
#define WT_ELEMS   (3 * NHID * NHID)  // packed weights, 196 KB

// W2[g][k4][c][j] = rk[(4*k4+j)*384 + g*128 + c]
// -> wave-load at (g,k4): 8 consecutive channels * 16B = contiguous 128B line
__global__ __launch_bounds__(256)
void pack_w_kernel(const float* __restrict__ rk, float* __restrict__ wt) {
    const int i = blockIdx.x * 256 + threadIdx.x;
    if (i < WT_ELEMS) {
        const int j  = i & 3;
        const int c  = (i >> 2) & 127;
        const int k4 = (i >> 9) & 31;
        const int g  = i >> 14;
        wt[i] = rk[(k4 * 4 + j) * 384 + g * NHID + c];
    }
}

template<int TR>
__global__ __launch_bounds__(BS, 4)
void vmc_gru_kernel(const float* __restrict__ gk,   // (2, 384)
                    const float* __restrict__ rk,   // (128, 384)
                    const float* __restrict__ gb,   // (2, 384)
                    const float* __restrict__ dw,   // (128, 2)
                    const float* __restrict__ db,   // (2,)
                    const float* __restrict__ u,    // (4096, 512)
                    const float* __restrict__ wt,   // packed (3,32,128,4)
                    float* __restrict__ out)        // samples then logp
{
    __shared__ float hsm[2][SPB][HPAD];   // h double-buffered, [s][k]
    __shared__ float part[16][8][4];      // per-wave 8-channel logit partials
    __shared__ int   prevs[SPB];

    const int tid = threadIdx.x;
    const int cg  = tid >> 3;             // channel 0..127
    const int p   = tid & 7;              // sample-pair slot
    const int s0  = p * 2;
    const int wv  = tid >> 6;             // wave 0..15

    for (int i = tid; i < SPB * HPAD; i += BS) (&hsm[0][0][0])[i] = 0.0f;
    if (tid < SPB) prevs[tid] = 0;
    __syncthreads();

    // per-thread constants for channel cg
    const float brz = gb[384 + cg];
    const float brr = gb[384 + 128 + cg];
    const float brh = gb[384 + 256 + cg];
    const float xzI = gb[cg],       xz0c = xzI + gk[cg],       xz1c = xzI + gk[384 + cg];
    const float xrI = gb[128 + cg], xr0c = xrI + gk[128 + cg], xr1c = xrI + gk[384 + 128 + cg];
    const float xhI = gb[256 + cg], xh0c = xhI + gk[256 + cg], xh1c = xhI + gk[384 + 256 + cg];
    const float dwc0 = dw[cg * 2], dwc1 = dw[cg * 2 + 1];
    const float db0 = db[0], db1 = db[1];

    const int fsamp = blockIdx.x * SPB + tid;   // valid for tid < 16
    float logp = 0.0f;
    int cur = 0;

    const float4* wz4 = (const float4*)wt + cg;          // g=0 plane
    const float4* wr4 = (const float4*)wt + 4096 + cg;   // g=1 plane
    const float4* wh4 = (const float4*)wt + 8192 + cg;   // g=2 plane
    const float* rkp = rk + cg;                          // fallback path

    for (int t = 0; t < NSTEPS; ++t) {
        // prefetch this step's u early; consumed ~GEMM-length later
        float ut = 0.0f;
        if (tid < SPB) ut = u[(size_t)fsamp * NSTEPS + t];

        // ---- GEMM: per (cg, 2 samples); chain bit-identical: bias init, k ascending
        float az0 = brz, az1 = brz;
        float ar0 = brr, ar1 = brr;
        float ah0 = brh, ah1 = brh;
        const float4* h0q = (const float4*)&hsm[cur][s0][0];
        const float4* h1q = (const float4*)&hsm[cur][s0 + 1][0];

        if (TR) {
            #pragma unroll 4
            for (int k4 = 0; k4 < 32; ++k4) {
                const float4 wz = wz4[k4 * 128];
                const float4 wr = wr4[k4 * 128];
                const float4 wh = wh4[k4 * 128];
                const float4 ha = h0q[k4];
                const float4 hb = h1q[k4];
                az0 = fmaf(wz.x, ha.x, az0); az1 = fmaf(wz.x, hb.x, az1);
                ar0 = fmaf(wr.x, ha.x, ar0); ar1 = fmaf(wr.x, hb.x, ar1);
                ah0 = fmaf(wh.x, ha.x, ah0); ah1 = fmaf(wh.x, hb.x, ah1);
                az0 = fmaf(wz.y, ha.y, az0); az1 = fmaf(wz.y, hb.y, az1);
                ar0 = fmaf(wr.y, ha.y, ar0); ar1 = fmaf(wr.y, hb.y, ar1);
                ah0 = fmaf(wh.y, ha.y, ah0); ah1 = fmaf(wh.y, hb.y, ah1);
                az0 = fmaf(wz.z, ha.z, az0); az1 = fmaf(wz.z, hb.z, az1);
                ar0 = fmaf(wr.z, ha.z, ar0); ar1 = fmaf(wr.z, hb.z, ar1);
                ah0 = fmaf(wh.z, ha.z, ah0); ah1 = fmaf(wh.z, hb.z, ah1);
                az0 = fmaf(wz.w, ha.w, az0); az1 = fmaf(wz.w, hb.w, az1);
                ar0 = fmaf(wr.w, ha.w, ar0); ar1 = fmaf(wr.w, hb.w, ar1);
                ah0 = fmaf(wh.w, ha.w, ah0); ah1 = fmaf(wh.w, hb.w, ah1);
            }
        } else {
            const float* wp = rkp;
            const float* h0p = &hsm[cur][s0][0];
            const float* h1p = &hsm[cur][s0 + 1][0];
            #pragma unroll 4
            for (int k = 0; k < NHID; ++k) {
                const float wz = wp[0];
                const float wr = wp[NHID];
                const float wh = wp[2 * NHID];
                const float ha = h0p[k];
                const float hb = h1p[k];
                az0 = fmaf(wz, ha, az0); az1 = fmaf(wz, hb, az1);
                ar0 = fmaf(wr, ha, ar0); ar1 = fmaf(wr, hb, ar1);
                ah0 = fmaf(wh, ha, ah0); ah1 = fmaf(wh, hb, ah1);
                wp += 3 * NHID;
            }
        }

        // ---- gates + state update (writes go to the OTHER h buffer)
        const int pv0 = prevs[s0], pv1 = prevs[s0 + 1];
        const float ho0 = hsm[cur][s0][cg];
        const float ho1 = hsm[cur][s0 + 1][cg];

        float xzA = pv0 ? xz1c : xz0c, xzB = pv1 ? xz1c : xz0c;
        float xrA = pv0 ? xr1c : xr0c, xrB = pv1 ? xr1c : xr0c;
        float xhA = pv0 ? xh1c : xh0c, xhB = pv1 ? xh1c : xh0c;
        if (t == 0) { xzA = xzI; xzB = xzI; xrA = xrI; xrB = xrI; xhA = xhI; xhB = xhI; }

        const float zA  = 1.0f / (1.0f + expf(-(xzA + az0)));
        const float rA  = 1.0f / (1.0f + expf(-(xrA + ar0)));
        const float hcA = tanhf(xhA + rA * ah0);
        const float hn0 = zA * ho0 + (1.0f - zA) * hcA;

        const float zB  = 1.0f / (1.0f + expf(-(xzB + az1)));
        const float rB  = 1.0f / (1.0f + expf(-(xrB + ar1)));
        const float hcB = tanhf(xhB + rB * ah1);
        const float hn1 = zB * ho1 + (1.0f - zB) * hcB;

        hsm[cur ^ 1][s0][cg]     = hn0;
        hsm[cur ^ 1][s0 + 1][cg] = hn1;

        float p00 = hn0 * dwc0, p01 = hn1 * dwc0;
        float p10 = hn0 * dwc1, p11 = hn1 * dwc1;

        // butterfly over the wave's 8 channels (cg bits at lane bits 3,4,5)
        #pragma unroll
        for (int off = 8; off < 64; off <<= 1) {
            p00 += __shfl_xor(p00, off);
            p01 += __shfl_xor(p01, off);
            p10 += __shfl_xor(p10, off);
            p11 += __shfl_xor(p11, off);
        }
        if ((tid & 63) < 8) {
            *(float4*)&part[wv][p][0] = make_float4(p00, p01, p10, p11);
        }
        __syncthreads();   // B1: partials + h_new visible

        // ---- softmax/sample/logp: one thread per sample
        if (tid < SPB) {
            const int sh = tid >> 1, lo = tid & 1;
            float l0 = db0, l1 = db1;
            #pragma unroll
            for (int j = 0; j < 8; ++j) {
                const float4 qa = *(const float4*)&part[2 * j][sh][0];
                const float4 qb = *(const float4*)&part[2 * j + 1][sh][0];
                const float a0 = lo ? qa.y : qa.x;
                const float b0 = lo ? qb.y : qb.x;
                const float a1 = lo ? qa.w : qa.z;
                const float b1 = lo ? qb.w : qb.z;
                l0 += (a0 + b0);
                l1 += (a1 + b1);
            }
            const float mx = fmaxf(l0, l1);
            const float e0 = expf(l0 - mx);
            const float e1 = expf(l1 - mx);
            const float inv = 1.0f / (e0 + e1);
            const float p1 = e1 * inv;
            const int st = (ut < p1) ? 1 : 0;
            const float psel = st ? p1 : (e0 * inv);
            logp += logf(psel + 1e-10f);
            out[(size_t)fsamp * NSTEPS + t] = (float)st;
            prevs[tid] = st;
        }
        __syncthreads();   // B2: prevs/sample published before next step
        cur ^= 1;
    }

    if (tid < SPB) out[SAMP_ELEMS + fsamp] = logp;
}

extern "C" void kernel_launch(void* const* d_in, const int* in_sizes, int n_in,
                              void* d_out, int out_size, void* d_ws, size_t ws_size,
                              hipStream_t stream) {
    const float* gk = (const float*)d_in[0];
    const float* rk = (const float*)d_in[1];
    const float* gb = (const float*)d_in[2];
    const float* dw = (const float*)d_in[3];
    const float* db = (const float*)d_in[4];
    const float* u  = (const float*)d_in[5];
    float* out = (float*)d_out;

    if (ws_size >= (size_t)WT_ELEMS * sizeof(float)) {
        float* wt = (float*)d_ws;
        pack_w_kernel<<<(WT_ELEMS + 255) / 256, 256, 0, stream>>>(rk, wt);
        vmc_gru_kernel<1><<<NBLK, BS, 0, stream>>>(gk, rk, gb, dw, db, u, wt, out);
    } else {
        vmc_gru_kernel<0><<<NBLK, BS, 0, stream>>>(gk, rk, gb, dw, db, u, rk, out);
    }
}

// Round 5
// 4440.076 us; speedup vs baseline: 1.4302x; 1.4302x over previous
//
#include <hip/hip_runtime.h>

#define NHID   128
#define NSTEPS 512
#define NSAMP  4096
#define SPB    16
#define BS     512
#define NBLK   (NSAMP / SPB)          // 256 blocks, 1 per CU
#define SAMP_ELEMS (NSAMP * NSTEPS)
#define WT_ELEMS   (3 * NHID * NHID)  // packed weights, 196 KB

// wt[g][k4][c][j] = rk[(4*k4+j)*384 + g*128 + c]
// R2 mapping (16 consecutive channels per wave): wave-load at (g,k4) covers
// 16 ch x 16B = 256B contiguous, broadcast x4 over sample-quads.
__global__ __launch_bounds__(256)
void pack_w_kernel(const float* __restrict__ rk, float* __restrict__ wt) {
    const int i = blockIdx.x * 256 + threadIdx.x;
    if (i < WT_ELEMS) {
        const int j  = i & 3;
        const int c  = (i >> 2) & 127;
        const int k4 = (i >> 9) & 31;
        const int g  = i >> 14;
        wt[i] = rk[(k4 * 4 + j) * 384 + g * NHID + c];
    }
}

template<int TR>
__global__ __launch_bounds__(BS, 1)
void vmc_gru_kernel(const float* __restrict__ gk,   // (2, 384)
                    const float* __restrict__ rk,   // (128, 384)
                    const float* __restrict__ gb,   // (2, 384)
                    const float* __restrict__ dw,   // (128, 2)
                    const float* __restrict__ db,   // (2,)
                    const float* __restrict__ u,    // (4096, 512)
                    const float* __restrict__ wt,   // packed (3,32,128,4)
                    float* __restrict__ out)        // samples then logp
{
    __shared__ float hsm[2][NHID][SPB];      // 16 KB, double-buffered h[k][s]
    __shared__ float part[2][8][SPB][2];     // 2 KB, double-buffered wave partials
    __shared__ float uld[NSTEPS][SPB];       // 32 KB, u transposed

    const int tid = threadIdx.x;
    const int cg  = tid >> 2;                // channel 0..127
    const int sq  = tid & 3;                 // sample-quad 0..3
    const int s0  = sq * 4;
    const int wv  = tid >> 6;                // wave 0..7

    // ---- stage u into LDS transposed: uld[t][s] = u[base+s][t]
    {
        const int sl = tid >> 5;             // 0..15
        const int t0 = (tid & 31) * 16;
        const float* up = u + (size_t)(blockIdx.x * SPB + sl) * NSTEPS + t0;
        const float4 a = ((const float4*)up)[0];
        const float4 b = ((const float4*)up)[1];
        const float4 c = ((const float4*)up)[2];
        const float4 d = ((const float4*)up)[3];
        const float tmp[16] = {a.x,a.y,a.z,a.w, b.x,b.y,b.z,b.w,
                               c.x,c.y,c.z,c.w, d.x,d.y,d.z,d.w};
        #pragma unroll
        for (int i = 0; i < 16; ++i) uld[t0 + i][sl] = tmp[i];
    }
    for (int i = tid; i < NHID * SPB; i += BS) (&hsm[0][0][0])[i] = 0.0f;
    __syncthreads();

    // per-thread constants for channel cg
    const float brz = gb[384 + cg];
    const float brr = gb[384 + 128 + cg];
    const float brh = gb[384 + 256 + cg];
    const float xzI = gb[cg],       xz0c = xzI + gk[cg],       xz1c = xzI + gk[384 + cg];
    const float xrI = gb[128 + cg], xr0c = xrI + gk[128 + cg], xr1c = xrI + gk[384 + 128 + cg];
    const float xhI = gb[256 + cg], xh0c = xhI + gk[256 + cg], xh1c = xhI + gk[384 + 256 + cg];
    const float dwc0 = dw[cg * 2], dwc1 = dw[cg * 2 + 1];
    const float db0 = db[0], db1 = db[1];

    const float4* wz4 = (const float4*)wt + cg;           // g=0 plane
    const float4* wr4 = (const float4*)wt + 4096 + cg;    // g=1 plane
    const float4* wh4 = (const float4*)wt + 8192 + cg;    // g=2 plane
    const float* rkp = rk + cg;                           // fallback path

    int   pv[4] = {0, 0, 0, 0};          // prev sample per owned sample (regs)
    float lg[4] = {0.f, 0.f, 0.f, 0.f};  // logp accumulators (regs)
    int cur = 0;

    for (int t = 0; t < NSTEPS; ++t) {
        // ---- GEMM: hg[c][s0..s0+3]; chain bit-identical: bias init, k ascending
        float az[4] = {brz, brz, brz, brz};
        float ar[4] = {brr, brr, brr, brr};
        float ah[4] = {brh, brh, brh, brh};

        if (TR) {
            #pragma unroll 4
            for (int k4 = 0; k4 < 32; ++k4) {
                const float4 wz = wz4[k4 * 128];
                const float4 wr = wr4[k4 * 128];
                const float4 wh = wh4[k4 * 128];
                const float4 h0 = *(const float4*)&hsm[cur][4 * k4 + 0][s0];
                const float4 h1 = *(const float4*)&hsm[cur][4 * k4 + 1][s0];
                const float4 h2 = *(const float4*)&hsm[cur][4 * k4 + 2][s0];
                const float4 h3 = *(const float4*)&hsm[cur][4 * k4 + 3][s0];
                const float hk0[4] = {h0.x, h0.y, h0.z, h0.w};
                const float hk1[4] = {h1.x, h1.y, h1.z, h1.w};
                const float hk2[4] = {h2.x, h2.y, h2.z, h2.w};
                const float hk3[4] = {h3.x, h3.y, h3.z, h3.w};
                #pragma unroll
                for (int j = 0; j < 4; ++j) az[j] = fmaf(wz.x, hk0[j], az[j]);
                #pragma unroll
                for (int j = 0; j < 4; ++j) ar[j] = fmaf(wr.x, hk0[j], ar[j]);
                #pragma unroll
                for (int j = 0; j < 4; ++j) ah[j] = fmaf(wh.x, hk0[j], ah[j]);
                #pragma unroll
                for (int j = 0; j < 4; ++j) az[j] = fmaf(wz.y, hk1[j], az[j]);
                #pragma unroll
                for (int j = 0; j < 4; ++j) ar[j] = fmaf(wr.y, hk1[j], ar[j]);
                #pragma unroll
                for (int j = 0; j < 4; ++j) ah[j] = fmaf(wh.y, hk1[j], ah[j]);
                #pragma unroll
                for (int j = 0; j < 4; ++j) az[j] = fmaf(wz.z, hk2[j], az[j]);
                #pragma unroll
                for (int j = 0; j < 4; ++j) ar[j] = fmaf(wr.z, hk2[j], ar[j]);
                #pragma unroll
                for (int j = 0; j < 4; ++j) ah[j] = fmaf(wh.z, hk2[j], ah[j]);
                #pragma unroll
                for (int j = 0; j < 4; ++j) az[j] = fmaf(wz.w, hk3[j], az[j]);
                #pragma unroll
                for (int j = 0; j < 4; ++j) ar[j] = fmaf(wr.w, hk3[j], ar[j]);
                #pragma unroll
                for (int j = 0; j < 4; ++j) ah[j] = fmaf(wh.w, hk3[j], ah[j]);
            }
        } else {
            const float* wp = rkp;
            #pragma unroll 4
            for (int k = 0; k < NHID; ++k) {
                const float wz = wp[0];
                const float wr = wp[NHID];
                const float wh = wp[2 * NHID];
                const float4 hv = *(const float4*)&hsm[cur][k][s0];
                const float hk[4] = {hv.x, hv.y, hv.z, hv.w};
                #pragma unroll
                for (int j = 0; j < 4; ++j) az[j] = fmaf(wz, hk[j], az[j]);
                #pragma unroll
                for (int j = 0; j < 4; ++j) ar[j] = fmaf(wr, hk[j], ar[j]);
                #pragma unroll
                for (int j = 0; j < 4; ++j) ah[j] = fmaf(wh, hk[j], ah[j]);
                wp += 3 * NHID;
            }
        }

        // ---- gates + state update
        const float4 ho = *(const float4*)&hsm[cur][cg][s0];
        const float hov[4] = {ho.x, ho.y, ho.z, ho.w};
        float hn[4], p0s[4], p1s[4];
        #pragma unroll
        for (int j = 0; j < 4; ++j) {
            float xz = pv[j] ? xz1c : xz0c;
            float xr = pv[j] ? xr1c : xr0c;
            float xh = pv[j] ? xh1c : xh0c;
            if (t == 0) { xz = xzI; xr = xrI; xh = xhI; }
            const float z  = 1.0f / (1.0f + expf(-(xz + az[j])));
            const float r  = 1.0f / (1.0f + expf(-(xr + ar[j])));
            const float hc = tanhf(xh + r * ah[j]);
            const float hnew = z * hov[j] + (1.0f - z) * hc;
            hn[j] = hnew;
            p0s[j] = hnew * dwc0;
            p1s[j] = hnew * dwc1;
        }
        *(float4*)&hsm[cur ^ 1][cg][s0] = make_float4(hn[0], hn[1], hn[2], hn[3]);

        // butterfly over the wave's 16 channels (lane bits [5:2] = cg)
        #pragma unroll
        for (int off = 4; off < 64; off <<= 1) {
            #pragma unroll
            for (int j = 0; j < 4; ++j) {
                p0s[j] += __shfl_xor(p0s[j], off);
                p1s[j] += __shfl_xor(p1s[j], off);
            }
        }
        const int pb = t & 1;
        if ((tid & 63) < 4) {
            *(float4*)&part[pb][wv][s0][0]     = make_float4(p0s[0], p1s[0], p0s[1], p1s[1]);
            *(float4*)&part[pb][wv][s0 + 2][0] = make_float4(p0s[2], p1s[2], p0s[3], p1s[3]);
        }
        __syncthreads();   // single barrier: h_new + partials visible

        // ---- redundant logit/sample phase: every thread, its own 4 samples
        float l0[4] = {db0, db0, db0, db0};
        float l1[4] = {db1, db1, db1, db1};
        #pragma unroll
        for (int w = 0; w < 8; ++w) {        // w-ascending sequential fold = R2 order
            const float4 qa = *(const float4*)&part[pb][w][s0][0];
            const float4 qb = *(const float4*)&part[pb][w][s0 + 2][0];
            l0[0] += qa.x; l1[0] += qa.y;
            l0[1] += qa.z; l1[1] += qa.w;
            l0[2] += qb.x; l1[2] += qb.y;
            l0[3] += qb.z; l1[3] += qb.w;
        }
        const float4 uu = *(const float4*)&uld[t][s0];
        const float uv[4] = {uu.x, uu.y, uu.z, uu.w};
        #pragma unroll
        for (int j = 0; j < 4; ++j) {
            const float mx = fmaxf(l0[j], l1[j]);
            const float e0 = expf(l0[j] - mx);
            const float e1 = expf(l1[j] - mx);
            const float inv = 1.0f / (e0 + e1);
            const float p1v = e1 * inv;
            const int st = (uv[j] < p1v) ? 1 : 0;
            const float psel = st ? p1v : (e0 * inv);
            lg[j] += logf(psel + 1e-10f);
            pv[j] = st;
            if (cg == 0)
                out[(size_t)(blockIdx.x * SPB + s0 + j) * NSTEPS + t] = (float)st;
        }
        cur ^= 1;
    }

    if (cg == 0) {
        #pragma unroll
        for (int j = 0; j < 4; ++j)
            out[SAMP_ELEMS + blockIdx.x * SPB + s0 + j] = lg[j];
    }
}

extern "C" void kernel_launch(void* const* d_in, const int* in_sizes, int n_in,
                              void* d_out, int out_size, void* d_ws, size_t ws_size,
                              hipStream_t stream) {
    const float* gk = (const float*)d_in[0];
    const float* rk = (const float*)d_in[1];
    const float* gb = (const float*)d_in[2];
    const float* dw = (const float*)d_in[3];
    const float* db = (const float*)d_in[4];
    const float* u  = (const float*)d_in[5];
    float* out = (float*)d_out;

    if (ws_size >= (size_t)WT_ELEMS * sizeof(float)) {
        float* wt = (float*)d_ws;
        pack_w_kernel<<<(WT_ELEMS + 255) / 256, 256, 0, stream>>>(rk, wt);
        vmc_gru_kernel<1><<<NBLK, BS, 0, stream>>>(gk, rk, gb, dw, db, u, wt, out);
    } else {
        vmc_gru_kernel<0><<<NBLK, BS, 0, stream>>>(gk, rk, gb, dw, db, u, rk, out);
    }
}

// Round 6
// 4227.844 us; speedup vs baseline: 1.5020x; 1.0502x over previous
//
#include <hip/hip_runtime.h>

#define NHID   128
#define NSTEPS 512
#define NSAMP  4096
#define SPB    16
#define BS     512
#define NBLK   (NSAMP / SPB)          // 256 blocks, 1 per CU
#define KL4    17                     // k4-chunks of W staged in LDS (of 32)
#define SAMP_ELEMS (NSAMP * NSTEPS)
#define WT_ELEMS   (3 * NHID * NHID)  // packed weights, 196 KB

typedef float v2f __attribute__((ext_vector_type(2)));
typedef float v4f __attribute__((ext_vector_type(4)));

static __device__ __forceinline__ v2f fma2(v2f a, v2f b, v2f c) {
#if defined(__has_builtin)
#if __has_builtin(__builtin_elementwise_fma)
    return __builtin_elementwise_fma(a, b, c);
#else
    return (v2f){fmaf(a.x, b.x, c.x), fmaf(a.y, b.y, c.y)};
#endif
#else
    return (v2f){fmaf(a.x, b.x, c.x), fmaf(a.y, b.y, c.y)};
#endif
}

// wt[g][k4][c][j] = rk[(4*k4+j)*384 + g*128 + c]
// wave-load at (g,k4): 16 ch x 16B = 256B contiguous, broadcast x4 over sample-quads.
__global__ __launch_bounds__(256)
void pack_w_kernel(const float* __restrict__ rk, float* __restrict__ wt) {
    const int i = blockIdx.x * 256 + threadIdx.x;
    if (i < WT_ELEMS) {
        const int j  = i & 3;
        const int c  = (i >> 2) & 127;
        const int k4 = (i >> 9) & 31;
        const int g  = i >> 14;
        wt[i] = rk[(k4 * 4 + j) * 384 + g * NHID + c];
    }
}

template<int TR>
__global__ __launch_bounds__(BS, 1)
void vmc_gru_kernel(const float* __restrict__ gk,   // (2, 384)
                    const float* __restrict__ rk,   // (128, 384)
                    const float* __restrict__ gb,   // (2, 384)
                    const float* __restrict__ dw,   // (128, 2)
                    const float* __restrict__ db,   // (2,)
                    const float* __restrict__ u,    // (4096, 512)
                    const float* __restrict__ wt,   // packed (3,32,128,4)
                    float* __restrict__ out)        // samples then logp
{
    __shared__ float  hsm[2][NHID][SPB];        // 16 KB, double-buffered h[k][s]
    __shared__ float  part[2][8][SPB][2];       // 2 KB, double-buffered wave partials
    __shared__ float  uld[NSTEPS][SPB];         // 32 KB, u transposed
    __shared__ float4 slds[3 * KL4 * NHID];     // 102 KB, W chunk: [g][k4<KL4][c]

    const int tid = threadIdx.x;
    const int cg  = tid >> 2;                // channel 0..127
    const int sq  = tid & 3;                 // sample-quad 0..3
    const int s0  = sq * 4;
    const int wv  = tid >> 6;                // wave 0..7

    // ---- stage u into LDS transposed: uld[t][s] = u[base+s][t]
    {
        const int sl = tid >> 5;             // 0..15
        const int t0 = (tid & 31) * 16;
        const float* up = u + (size_t)(blockIdx.x * SPB + sl) * NSTEPS + t0;
        const float4 a = ((const float4*)up)[0];
        const float4 b = ((const float4*)up)[1];
        const float4 c = ((const float4*)up)[2];
        const float4 d = ((const float4*)up)[3];
        const float tmp[16] = {a.x,a.y,a.z,a.w, b.x,b.y,b.z,b.w,
                               c.x,c.y,c.z,c.w, d.x,d.y,d.z,d.w};
        #pragma unroll
        for (int i = 0; i < 16; ++i) uld[t0 + i][sl] = tmp[i];
    }
    // ---- stage first KL4 k4-chunks of all 3 gate planes into LDS (once)
    if (TR) {
        const float4* wt4 = (const float4*)wt;
        for (int i = tid; i < 3 * KL4 * NHID; i += BS) {
            const int g  = i / (KL4 * NHID);
            const int r  = i - g * (KL4 * NHID);
            slds[i] = wt4[g * 4096 + r];     // r = k4*128 + c, k4 < KL4
        }
    }
    for (int i = tid; i < NHID * SPB; i += BS) (&hsm[0][0][0])[i] = 0.0f;
    __syncthreads();

    // per-thread constants for channel cg
    const float brz = gb[384 + cg];
    const float brr = gb[384 + 128 + cg];
    const float brh = gb[384 + 256 + cg];
    const float xzI = gb[cg],       xz0c = xzI + gk[cg],       xz1c = xzI + gk[384 + cg];
    const float xrI = gb[128 + cg], xr0c = xrI + gk[128 + cg], xr1c = xrI + gk[384 + 128 + cg];
    const float xhI = gb[256 + cg], xh0c = xhI + gk[256 + cg], xh1c = xhI + gk[384 + 256 + cg];
    const float dwc0 = dw[cg * 2], dwc1 = dw[cg * 2 + 1];
    const float db0 = db[0], db1 = db[1];

    const v4f* lz = (const v4f*)slds + cg;                 // LDS g=0 plane
    const v4f* lr = (const v4f*)slds + KL4 * 128 + cg;     // LDS g=1 plane
    const v4f* lh = (const v4f*)slds + 2 * KL4 * 128 + cg; // LDS g=2 plane
    const v4f* wz4 = (const v4f*)wt + cg;                  // global g=0 plane
    const v4f* wr4 = (const v4f*)wt + 4096 + cg;           // global g=1 plane
    const v4f* wh4 = (const v4f*)wt + 8192 + cg;           // global g=2 plane
    const float* rkp = rk + cg;                            // fallback path

    int   pv[4] = {0, 0, 0, 0};
    float lg[4] = {0.f, 0.f, 0.f, 0.f};
    int cur = 0;

    for (int t = 0; t < NSTEPS; ++t) {
        // ---- GEMM: hg[c][s0..s0+3]; per-(gate,sample) chain: bias init, k ascending,
        // fmaf per component (pk_fma packs across samples -> bit-identical chains)
        v2f az01 = {brz, brz}, az23 = {brz, brz};
        v2f ar01 = {brr, brr}, ar23 = {brr, brr};
        v2f ah01 = {brh, brh}, ah23 = {brh, brh};

#define GEMM_K4(WZ, WR, WH, K4) do {                                        \
    const v4f h_0 = *(const v4f*)&hsm[cur][4*(K4)+0][s0];                   \
    const v4f h_1 = *(const v4f*)&hsm[cur][4*(K4)+1][s0];                   \
    const v4f h_2 = *(const v4f*)&hsm[cur][4*(K4)+2][s0];                   \
    const v4f hh[4] = {h_0, h_1, h_2, *(const v4f*)&hsm[cur][4*(K4)+3][s0]};\
    _Pragma("unroll")                                                        \
    for (int kk = 0; kk < 4; ++kk) {                                         \
        const v2f hlo = hh[kk].xy;                                           \
        const v2f hhi = hh[kk].zw;                                           \
        const v2f wz2 = {(WZ)[kk], (WZ)[kk]};                                \
        const v2f wr2 = {(WR)[kk], (WR)[kk]};                                \
        const v2f wh2 = {(WH)[kk], (WH)[kk]};                                \
        az01 = fma2(wz2, hlo, az01); az23 = fma2(wz2, hhi, az23);            \
        ar01 = fma2(wr2, hlo, ar01); ar23 = fma2(wr2, hhi, ar23);            \
        ah01 = fma2(wh2, hlo, ah01); ah23 = fma2(wh2, hhi, ah23);            \
    }                                                                         \
} while (0)

        if (TR) {
            #pragma unroll 4
            for (int k4 = 0; k4 < KL4; ++k4) {       // LDS-resident chunk
                const v4f wz = lz[k4 * 128];
                const v4f wr = lr[k4 * 128];
                const v4f wh = lh[k4 * 128];
                GEMM_K4(wz, wr, wh, k4);
            }
            #pragma unroll 4
            for (int k4 = KL4; k4 < 32; ++k4) {      // global (L1/L2) chunk
                const v4f wz = wz4[k4 * 128];
                const v4f wr = wr4[k4 * 128];
                const v4f wh = wh4[k4 * 128];
                GEMM_K4(wz, wr, wh, k4);
            }
        } else {
            const float* wp = rkp;
            #pragma unroll 4
            for (int k = 0; k < NHID; ++k) {
                const float wz = wp[0];
                const float wr = wp[NHID];
                const float wh = wp[2 * NHID];
                const v4f hv = *(const v4f*)&hsm[cur][k][s0];
                const v2f hlo = hv.xy, hhi = hv.zw;
                const v2f wz2 = {wz, wz}, wr2 = {wr, wr}, wh2 = {wh, wh};
                az01 = fma2(wz2, hlo, az01); az23 = fma2(wz2, hhi, az23);
                ar01 = fma2(wr2, hlo, ar01); ar23 = fma2(wr2, hhi, ar23);
                ah01 = fma2(wh2, hlo, ah01); ah23 = fma2(wh2, hhi, ah23);
                wp += 3 * NHID;
            }
        }
#undef GEMM_K4

        const float az[4] = {az01.x, az01.y, az23.x, az23.y};
        const float ar[4] = {ar01.x, ar01.y, ar23.x, ar23.y};
        const float ah[4] = {ah01.x, ah01.y, ah23.x, ah23.y};

        // ---- gates + state update
        const v4f ho = *(const v4f*)&hsm[cur][cg][s0];
        const float hov[4] = {ho.x, ho.y, ho.z, ho.w};
        float hn[4], p0s[4], p1s[4];
        #pragma unroll
        for (int j = 0; j < 4; ++j) {
            float xz = pv[j] ? xz1c : xz0c;
            float xr = pv[j] ? xr1c : xr0c;
            float xh = pv[j] ? xh1c : xh0c;
            if (t == 0) { xz = xzI; xr = xrI; xh = xhI; }
            const float z  = 1.0f / (1.0f + expf(-(xz + az[j])));
            const float r  = 1.0f / (1.0f + expf(-(xr + ar[j])));
            const float hc = tanhf(xh + r * ah[j]);
            const float hnew = z * hov[j] + (1.0f - z) * hc;
            hn[j] = hnew;
            p0s[j] = hnew * dwc0;
            p1s[j] = hnew * dwc1;
        }
        *(v4f*)&hsm[cur ^ 1][cg][s0] = (v4f){hn[0], hn[1], hn[2], hn[3]};

        // butterfly over the wave's 16 channels (lane bits [5:2] = cg)
        #pragma unroll
        for (int off = 4; off < 64; off <<= 1) {
            #pragma unroll
            for (int j = 0; j < 4; ++j) {
                p0s[j] += __shfl_xor(p0s[j], off);
                p1s[j] += __shfl_xor(p1s[j], off);
            }
        }
        const int pb = t & 1;
        if ((tid & 63) < 4) {
            *(float4*)&part[pb][wv][s0][0]     = make_float4(p0s[0], p1s[0], p0s[1], p1s[1]);
            *(float4*)&part[pb][wv][s0 + 2][0] = make_float4(p0s[2], p1s[2], p0s[3], p1s[3]);
        }
        __syncthreads();   // single barrier: h_new + partials visible

        // ---- redundant logit/sample phase: every thread, its own 4 samples
        float l0[4] = {db0, db0, db0, db0};
        float l1[4] = {db1, db1, db1, db1};
        #pragma unroll
        for (int w = 0; w < 8; ++w) {        // w-ascending sequential fold
            const float4 qa = *(const float4*)&part[pb][w][s0][0];
            const float4 qb = *(const float4*)&part[pb][w][s0 + 2][0];
            l0[0] += qa.x; l1[0] += qa.y;
            l0[1] += qa.z; l1[1] += qa.w;
            l0[2] += qb.x; l1[2] += qb.y;
            l0[3] += qb.z; l1[3] += qb.w;
        }
        const float4 uu = *(const float4*)&uld[t][s0];
        const float uv[4] = {uu.x, uu.y, uu.z, uu.w};
        #pragma unroll
        for (int j = 0; j < 4; ++j) {
            const float mx = fmaxf(l0[j], l1[j]);
            const float e0 = expf(l0[j] - mx);
            const float e1 = expf(l1[j] - mx);
            const float inv = 1.0f / (e0 + e1);
            const float p1v = e1 * inv;
            const int st = (uv[j] < p1v) ? 1 : 0;
            const float psel = st ? p1v : (e0 * inv);
            lg[j] += logf(psel + 1e-10f);
            pv[j] = st;
            if (cg == 0)
                out[(size_t)(blockIdx.x * SPB + s0 + j) * NSTEPS + t] = (float)st;
        }
        cur ^= 1;
    }

    if (cg == 0) {
        #pragma unroll
        for (int j = 0; j < 4; ++j)
            out[SAMP_ELEMS + blockIdx.x * SPB + s0 + j] = lg[j];
    }
}

extern "C" void kernel_launch(void* const* d_in, const int* in_sizes, int n_in,
                              void* d_out, int out_size, void* d_ws, size_t ws_size,
                              hipStream_t stream) {
    const float* gk = (const float*)d_in[0];
    const float* rk = (const float*)d_in[1];
    const float* gb = (const float*)d_in[2];
    const float* dw = (const float*)d_in[3];
    const float* db = (const float*)d_in[4];
    const float* u  = (const float*)d_in[5];
    float* out = (float*)d_out;

    if (ws_size >= (size_t)WT_ELEMS * sizeof(float)) {
        float* wt = (float*)d_ws;
        pack_w_kernel<<<(WT_ELEMS + 255) / 256, 256, 0, stream>>>(rk, wt);
        vmc_gru_kernel<1><<<NBLK, BS, 0, stream>>>(gk, rk, gb, dw, db, u, wt, out);
    } else {
        vmc_gru_kernel<0><<<NBLK, BS, 0, stream>>>(gk, rk, gb, dw, db, u, rk, out);
    }
}

// Round 8
// 3743.316 us; speedup vs baseline: 1.6964x; 1.1294x over previous
//
#include <hip/hip_runtime.h>

#define NHID   128
#define NSTEPS 512
#define NSAMP  4096
#define SPB    16
#define BS     512
#define NBLK   (NSAMP / SPB)          // 256 blocks, 1 per CU
#define KL4    17                     // k4-chunks of W staged in LDS (of 32)
#define SAMP_ELEMS (NSAMP * NSTEPS)
#define WT_ELEMS   (3 * NHID * NHID)  // packed weights, 196 KB

typedef float v2f __attribute__((ext_vector_type(2)));
typedef float v4f __attribute__((ext_vector_type(4)));

// packed fma, broadcast LOW half of weight pair to both lanes:
//   acc.lo += w.lo*h.lo ; acc.hi += w.lo*h.hi
#define PK_LO(ACC, W2, H2) \
    asm("v_pk_fma_f32 %0, %1, %2, %0 op_sel:[0,0,0] op_sel_hi:[0,1,1]" \
        : "+v"(ACC) : "v"(W2), "v"(H2))
// broadcast HIGH half of weight pair:
#define PK_HI(ACC, W2, H2) \
    asm("v_pk_fma_f32 %0, %1, %2, %0 op_sel:[1,0,0] op_sel_hi:[1,1,1]" \
        : "+v"(ACC) : "v"(W2), "v"(H2))

template<int IMM>
__device__ __forceinline__ float swz(float x) {
    return __int_as_float(__builtin_amdgcn_ds_swizzle(__float_as_int(x), IMM));
}

// wt[g][k4][c][j] = rk[(4*k4+j)*384 + g*128 + c]
__global__ __launch_bounds__(256)
void pack_w_kernel(const float* __restrict__ rk, float* __restrict__ wt) {
    const int i = blockIdx.x * 256 + threadIdx.x;
    if (i < WT_ELEMS) {
        const int j  = i & 3;
        const int c  = (i >> 2) & 127;
        const int k4 = (i >> 9) & 31;
        const int g  = i >> 14;
        wt[i] = rk[(k4 * 4 + j) * 384 + g * NHID + c];
    }
}

template<int TR>
__global__ __launch_bounds__(BS, 2)
void vmc_gru_kernel(const float* __restrict__ gk,   // (2, 384)
                    const float* __restrict__ rk,   // (128, 384)
                    const float* __restrict__ gb,   // (2, 384)
                    const float* __restrict__ dw,   // (128, 2)
                    const float* __restrict__ db,   // (2,)
                    const float* __restrict__ u,    // (4096, 512)
                    const float* __restrict__ wt,   // packed (3,32,128,4)
                    float* __restrict__ out)        // samples then logp
{
    __shared__ float hsm[2][NHID][SPB];        // 16 KB, double-buffered h[k][s]
    __shared__ float part[2][8][SPB][2];       // 2 KB
    __shared__ float uld[NSTEPS][SPB];         // 32 KB, u transposed
    __shared__ v4f   slds[3 * KL4 * NHID];     // 102 KB, W chunk [g][k4<KL4][c]

    const int tid = threadIdx.x;
    const int cg  = tid >> 2;                // channel 0..127
    const int sq  = tid & 3;                 // sample-quad
    const int s0  = sq * 4;
    const int wv  = tid >> 6;                // wave 0..7

    // ---- stage u transposed
    {
        const int sl = tid >> 5;
        const int t0 = (tid & 31) * 16;
        const float* up = u + (size_t)(blockIdx.x * SPB + sl) * NSTEPS + t0;
        const float4 a = ((const float4*)up)[0];
        const float4 b = ((const float4*)up)[1];
        const float4 c = ((const float4*)up)[2];
        const float4 d = ((const float4*)up)[3];
        const float tmp[16] = {a.x,a.y,a.z,a.w, b.x,b.y,b.z,b.w,
                               c.x,c.y,c.z,c.w, d.x,d.y,d.z,d.w};
        #pragma unroll
        for (int i = 0; i < 16; ++i) uld[t0 + i][sl] = tmp[i];
    }
    // ---- stage first KL4 k4-chunks of W into LDS (once)
    if (TR) {
        const v4f* wt4 = (const v4f*)wt;
        for (int i = tid; i < 3 * KL4 * NHID; i += BS) {
            const int g = i / (KL4 * NHID);
            const int r = i - g * (KL4 * NHID);
            slds[i] = wt4[g * 4096 + r];
        }
    }
    for (int i = tid; i < NHID * SPB; i += BS) (&hsm[0][0][0])[i] = 0.0f;
    __syncthreads();

    const float brz = gb[384 + cg];
    const float brr = gb[384 + 128 + cg];
    const float brh = gb[384 + 256 + cg];
    const float xzI = gb[cg],       xz0c = xzI + gk[cg],       xz1c = xzI + gk[384 + cg];
    const float xrI = gb[128 + cg], xr0c = xrI + gk[128 + cg], xr1c = xrI + gk[384 + 128 + cg];
    const float xhI = gb[256 + cg], xh0c = xhI + gk[256 + cg], xh1c = xhI + gk[384 + 256 + cg];
    const float dwc0 = dw[cg * 2], dwc1 = dw[cg * 2 + 1];
    const float db0 = db[0], db1 = db[1];

    const v4f* lz = slds + cg;                     // LDS planes
    const v4f* lr = slds + KL4 * 128 + cg;
    const v4f* lh = slds + 2 * KL4 * 128 + cg;
    const v4f* wz4 = (const v4f*)wt + cg;          // global planes
    const v4f* wr4 = (const v4f*)wt + 4096 + cg;
    const v4f* wh4 = (const v4f*)wt + 8192 + cg;
    const float* rkp = rk + cg;                    // fallback

    int   pv[4] = {0, 0, 0, 0};
    float lg[4] = {0.f, 0.f, 0.f, 0.f};
    float pr[4] = {1.f, 1.f, 1.f, 1.f};            // 8-step psel product
    int cur = 0;

    for (int t = 0; t < NSTEPS; ++t) {
        v2f az01 = {brz, brz}, az23 = {brz, brz};
        v2f ar01 = {brr, brr}, ar23 = {brr, brr};
        v2f ah01 = {brh, brh}, ah23 = {brh, brh};
        const float* hb = &hsm[cur][0][0];

#define GEMM_K4(WZ, WR, WH, K4) do {                                      \
    const v4f h0 = *(const v4f*)(hb + (4*(K4)+0)*SPB + s0);               \
    const v4f h1 = *(const v4f*)(hb + (4*(K4)+1)*SPB + s0);               \
    const v4f h2 = *(const v4f*)(hb + (4*(K4)+2)*SPB + s0);               \
    const v4f h3 = *(const v4f*)(hb + (4*(K4)+3)*SPB + s0);               \
    const v2f wzA = (WZ).xy, wzB = (WZ).zw;                               \
    const v2f wrA = (WR).xy, wrB = (WR).zw;                               \
    const v2f whA = (WH).xy, whB = (WH).zw;                               \
    PK_LO(az01, wzA, h0.xy); PK_LO(az23, wzA, h0.zw);                     \
    PK_LO(ar01, wrA, h0.xy); PK_LO(ar23, wrA, h0.zw);                     \
    PK_LO(ah01, whA, h0.xy); PK_LO(ah23, whA, h0.zw);                     \
    PK_HI(az01, wzA, h1.xy); PK_HI(az23, wzA, h1.zw);                     \
    PK_HI(ar01, wrA, h1.xy); PK_HI(ar23, wrA, h1.zw);                     \
    PK_HI(ah01, whA, h1.xy); PK_HI(ah23, whA, h1.zw);                     \
    PK_LO(az01, wzB, h2.xy); PK_LO(az23, wzB, h2.zw);                     \
    PK_LO(ar01, wrB, h2.xy); PK_LO(ar23, wrB, h2.zw);                     \
    PK_LO(ah01, whB, h2.xy); PK_LO(ah23, whB, h2.zw);                     \
    PK_HI(az01, wzB, h3.xy); PK_HI(az23, wzB, h3.zw);                     \
    PK_HI(ar01, wrB, h3.xy); PK_HI(ar23, wrB, h3.zw);                     \
    PK_HI(ah01, whB, h3.xy); PK_HI(ah23, whB, h3.zw);                     \
} while (0)

        if (TR) {
            #pragma unroll 4
            for (int k4 = 0; k4 < KL4; ++k4) {        // LDS-resident chunk
                const v4f wz = lz[k4 * 128];
                const v4f wr = lr[k4 * 128];
                const v4f wh = lh[k4 * 128];
                GEMM_K4(wz, wr, wh, k4);
            }
            #pragma unroll
            for (int k4 = KL4; k4 < 32; ++k4) {       // global chunk (loads hoist)
                const v4f wz = wz4[k4 * 128];
                const v4f wr = wr4[k4 * 128];
                const v4f wh = wh4[k4 * 128];
                GEMM_K4(wz, wr, wh, k4);
            }
        } else {
            const float* wp = rkp;
            #pragma unroll 4
            for (int k = 0; k < NHID; ++k) {
                const float wzs = wp[0];
                const float wrs = wp[NHID];
                const float whs = wp[2 * NHID];
                const v4f hv = *(const v4f*)(hb + k * SPB + s0);
                const float hk[4] = {hv.x, hv.y, hv.z, hv.w};
                float azs[4] = {az01.x, az01.y, az23.x, az23.y};
                float ars[4] = {ar01.x, ar01.y, ar23.x, ar23.y};
                float ahs[4] = {ah01.x, ah01.y, ah23.x, ah23.y};
                #pragma unroll
                for (int j = 0; j < 4; ++j) azs[j] = fmaf(wzs, hk[j], azs[j]);
                #pragma unroll
                for (int j = 0; j < 4; ++j) ars[j] = fmaf(wrs, hk[j], ars[j]);
                #pragma unroll
                for (int j = 0; j < 4; ++j) ahs[j] = fmaf(whs, hk[j], ahs[j]);
                az01 = (v2f){azs[0], azs[1]}; az23 = (v2f){azs[2], azs[3]};
                ar01 = (v2f){ars[0], ars[1]}; ar23 = (v2f){ars[2], ars[3]};
                ah01 = (v2f){ahs[0], ahs[1]}; ah23 = (v2f){ahs[2], ahs[3]};
                wp += 3 * NHID;
            }
        }
#undef GEMM_K4

        const float az[4] = {az01.x, az01.y, az23.x, az23.y};
        const float ar[4] = {ar01.x, ar01.y, ar23.x, ar23.y};
        const float ah[4] = {ah01.x, ah01.y, ah23.x, ah23.y};

        // ---- gates + state update
        const v4f ho = *(const v4f*)(hb + cg * SPB + s0);
        const float hov[4] = {ho.x, ho.y, ho.z, ho.w};
        float hn[4], p0s[4], p1s[4];
        #pragma unroll
        for (int j = 0; j < 4; ++j) {
            float xz = pv[j] ? xz1c : xz0c;
            float xr = pv[j] ? xr1c : xr0c;
            float xh = pv[j] ? xh1c : xh0c;
            if (t == 0) { xz = xzI; xr = xrI; xh = xhI; }
            const float z  = 1.0f / (1.0f + expf(-(xz + az[j])));
            const float r  = 1.0f / (1.0f + expf(-(xr + ar[j])));
            const float hc = tanhf(xh + r * ah[j]);
            const float hnew = z * hov[j] + (1.0f - z) * hc;
            hn[j] = hnew;
            p0s[j] = hnew * dwc0;
            p1s[j] = hnew * dwc1;
        }
        *(v4f*)&hsm[cur ^ 1][cg][s0] = (v4f){hn[0], hn[1], hn[2], hn[3]};

        // butterfly over 16 channels: xor 4,8,16 via ds_swizzle imm, xor 32 via shfl
        #pragma unroll
        for (int j = 0; j < 4; ++j) {
            p0s[j] += swz<0x101F>(p0s[j]);  p1s[j] += swz<0x101F>(p1s[j]);
            p0s[j] += swz<0x201F>(p0s[j]);  p1s[j] += swz<0x201F>(p1s[j]);
            p0s[j] += swz<0x401F>(p0s[j]);  p1s[j] += swz<0x401F>(p1s[j]);
            p0s[j] += __shfl_xor(p0s[j], 32);
            p1s[j] += __shfl_xor(p1s[j], 32);
        }
        const int pb = t & 1;
        if ((tid & 63) < 4) {
            *(float4*)&part[pb][wv][s0][0]     = make_float4(p0s[0], p1s[0], p0s[1], p1s[1]);
            *(float4*)&part[pb][wv][s0 + 2][0] = make_float4(p0s[2], p1s[2], p0s[3], p1s[3]);
        }
        __syncthreads();   // single barrier: h_new + partials visible

        // ---- redundant logit/sample phase: every thread, its own 4 samples
        float l0[4] = {db0, db0, db0, db0};
        float l1[4] = {db1, db1, db1, db1};
        #pragma unroll
        for (int w = 0; w < 8; ++w) {
            const float4 qa = *(const float4*)&part[pb][w][s0][0];
            const float4 qb = *(const float4*)&part[pb][w][s0 + 2][0];
            l0[0] += qa.x; l1[0] += qa.y;
            l0[1] += qa.z; l1[1] += qa.w;
            l0[2] += qb.x; l1[2] += qb.y;
            l0[3] += qb.z; l1[3] += qb.w;
        }
        const float4 uu = *(const float4*)&uld[t][s0];
        const float uv[4] = {uu.x, uu.y, uu.z, uu.w};
        #pragma unroll
        for (int j = 0; j < 4; ++j) {
            const float mx = fmaxf(l0[j], l1[j]);
            const float e0 = expf(l0[j] - mx);
            const float e1 = expf(l1[j] - mx);
            const float inv = 1.0f / (e0 + e1);
            const float p1v = e1 * inv;
            const int st = (uv[j] < p1v) ? 1 : 0;
            const float psel = st ? p1v : (e0 * inv);
            pr[j] *= (psel + 1e-10f);
            pv[j] = st;
            if (cg == 0)
                out[(size_t)(blockIdx.x * SPB + s0 + j) * NSTEPS + t] = (float)st;
        }
        if ((t & 7) == 7) {     // batched log: log(prod) == sum(log) up to rounding
            #pragma unroll
            for (int j = 0; j < 4; ++j) { lg[j] += logf(pr[j]); pr[j] = 1.0f; }
        }
        cur ^= 1;
    }

    if (cg == 0) {
        #pragma unroll
        for (int j = 0; j < 4; ++j)
            out[SAMP_ELEMS + blockIdx.x * SPB + s0 + j] = lg[j];
    }
}

extern "C" void kernel_launch(void* const* d_in, const int* in_sizes, int n_in,
                              void* d_out, int out_size, void* d_ws, size_t ws_size,
                              hipStream_t stream) {
    const float* gk = (const float*)d_in[0];
    const float* rk = (const float*)d_in[1];
    const float* gb = (const float*)d_in[2];
    const float* dw = (const float*)d_in[3];
    const float* db = (const float*)d_in[4];
    const float* u  = (const float*)d_in[5];
    float* out = (float*)d_out;

    if (ws_size >= (size_t)WT_ELEMS * sizeof(float)) {
        float* wt = (float*)d_ws;
        pack_w_kernel<<<(WT_ELEMS + 255) / 256, 256, 0, stream>>>(rk, wt);
        vmc_gru_kernel<1><<<NBLK, BS, 0, stream>>>(gk, rk, gb, dw, db, u, wt, out);
    } else {
        vmc_gru_kernel<0><<<NBLK, BS, 0, stream>>>(gk, rk, gb, dw, db, u, rk, out);
    }
}